// Round 3
// baseline (214.926 us; speedup 1.0000x reference)
//
#include <hip/hip_runtime.h>

// AttentionBlock: B=8, C=128, H=W=128, GROUPS=8, HEADS=8, HEAD_DIM=16
// R2 restructure:
//  - A-operands (w_in*s, w_eff) precomputed as bf16 in global ws; waves load
//    A-fragments directly (no LDS staging) -> LDS 70KB->35KB -> 4 blocks/CU.
//  - K2 caches h1^T (bf16, [b][tile][p][k]) in ws; K4 no longer recomputes
//    GEMM1 -- reads B-fragments straight from global h1t.
//  - K4 epilogue via bf16 LDS tile -> float4 loads/stores.

#define NPOS 16384          // 128*128 spatial
#define PITCH 136           // LDS row pitch in ushorts

typedef short short8 __attribute__((ext_vector_type(8)));   // 8 bf16 (4 VGPRs)
typedef float f32x4 __attribute__((ext_vector_type(4)));

__device__ __forceinline__ unsigned short f2bf(float f) {
    union { float f; unsigned u; } v; v.f = f;
    unsigned r = (v.u + 0x7fffu + ((v.u >> 16) & 1u)) >> 16;
    return (unsigned short)r;
}
__device__ __forceinline__ float bf2f(unsigned short h) {
    union { unsigned u; float f; } v; v.u = ((unsigned)h) << 16;
    return v.f;
}

// ---------------- K1: per-(b,g) sum / sumsq ----------------
__global__ __launch_bounds__(256) void k_stats(const float* __restrict__ x,
                                               float* __restrict__ stats) {
    const float4* p = (const float4*)(x + (size_t)blockIdx.x * 16384);
    int t = threadIdx.x;
    float s1 = 0.f, s2 = 0.f;
#pragma unroll
    for (int j = 0; j < 16; ++j) {
        float4 v = p[t + j * 256];
        s1 += v.x + v.y + v.z + v.w;
        s2 += v.x * v.x + v.y * v.y + v.z * v.z + v.w * v.w;
    }
    for (int off = 32; off; off >>= 1) {
        s1 += __shfl_down(s1, off);
        s2 += __shfl_down(s2, off);
    }
    __shared__ float r1[4], r2[4];
    int wv = t >> 6;
    if ((t & 63) == 0) { r1[wv] = s1; r2[wv] = s2; }
    __syncthreads();
    if (t == 0) {
        s1 = r1[0] + r1[1] + r1[2] + r1[3];
        s2 = r2[0] + r2[1] + r2[2] + r2[3];
        int bg = blockIdx.x >> 4;
        atomicAdd(&stats[bg * 2 + 0], s1);
        atomicAdd(&stats[bg * 2 + 1], s2);
    }
}

// ---------------- K1b: s,v and Asb = bf16(w_in * s) ----------------
__global__ __launch_bounds__(256) void k_prep(const float* __restrict__ stats,
                                              const float* __restrict__ gn_w,
                                              const float* __restrict__ gn_b,
                                              const float* __restrict__ w_in,
                                              const float* __restrict__ b_in,
                                              float* __restrict__ vA,
                                              unsigned short* __restrict__ Asb) {
    int b = blockIdx.x, t = threadIdx.x;
    __shared__ float ss[128], tl[128];
    if (t < 128) {
        int g = t >> 4;
        float s1 = stats[(b * 8 + g) * 2 + 0];
        float s2 = stats[(b * 8 + g) * 2 + 1];
        const float invN = 1.0f / 262144.0f;
        float mean = s1 * invN;
        float var = s2 * invN - mean * mean;
        float rstd = rsqrtf(var + 1e-5f);
        float s = gn_w[t] * rstd;
        ss[t] = s;
        tl[t] = gn_b[t] - mean * s;
    }
    __syncthreads();
    if (t < 128) {
        float v = b_in[t];
        const float* wr = w_in + t * 128;
#pragma unroll 8
        for (int k = 0; k < 128; ++k) v += wr[k] * tl[k];
        vA[b * 128 + t] = v;
    }
    unsigned short* ab = Asb + b * 16384;
    const float4* w4 = (const float4*)w_in;
#pragma unroll
    for (int i = 0; i < 16; ++i) {
        int idx = t + i * 256;
        int c = idx >> 5, k4 = idx & 31;
        float4 w = w4[idx];
        ushort4 o;
        o.x = f2bf(w.x * ss[k4 * 4 + 0]);
        o.y = f2bf(w.y * ss[k4 * 4 + 1]);
        o.z = f2bf(w.z * ss[k4 * 4 + 2]);
        o.w = f2bf(w.w * ss[k4 * 4 + 3]);
        *(ushort4*)&ab[c * 128 + k4 * 4] = o;
    }
}

// ---------------- K2: GEMM1 -> h1t cache + partial S (atomics) ----------------
__global__ __launch_bounds__(256, 4) void k_gemm1_scores(const float* __restrict__ x,
                                                         const unsigned short* __restrict__ Asb,
                                                         const float* __restrict__ vA,
                                                         unsigned short* __restrict__ h1t,
                                                         float* __restrict__ Sg) {
    __shared__ unsigned short Xt[128 * PITCH];
    __shared__ float v_s[128];

    const int t = threadIdx.x;
    const int lane = t & 63, wv = t >> 6;
    const int q = lane >> 4, i16 = lane & 15;
    const int b = blockIdx.x >> 7;
    const int tile = blockIdx.x & 127;
    const int p0 = tile << 7;

    if (t < 128) v_s[t] = vA[b * 128 + t];

    // stage Xt[p][k] = bf16(x[k][p0+p])  (transpose)
    {
        const float* xb = x + (size_t)b * (128 * NPOS) + p0;
#pragma unroll
        for (int i = 0; i < 16; ++i) {
            int p = ((i & 1) << 6) + lane;
            int kq = (wv << 3) + (i >> 1);
            const float* col = xb + (size_t)(kq * 4) * NPOS + p;
            float a0 = col[0];
            float a1 = col[NPOS];
            float a2 = col[2 * NPOS];
            float a3 = col[3 * NPOS];
            ushort4 o; o.x = f2bf(a0); o.y = f2bf(a1); o.z = f2bf(a2); o.w = f2bf(a3);
            *(ushort4*)&Xt[p * PITCH + kq * 4] = o;
        }
    }
    __syncthreads();

    const unsigned short* ab = Asb + b * 16384;

    f32x4 acc[2][8];
#pragma unroll
    for (int a = 0; a < 2; ++a)
#pragma unroll
        for (int pt = 0; pt < 8; ++pt) acc[a][pt] = (f32x4){0.f, 0.f, 0.f, 0.f};

#pragma unroll
    for (int ks = 0; ks < 4; ++ks) {
        short8 a0 = *(const short8*)&ab[(wv * 32 + i16) * 128 + ks * 32 + q * 8];
        short8 a1 = *(const short8*)&ab[(wv * 32 + 16 + i16) * 128 + ks * 32 + q * 8];
#pragma unroll
        for (int pt = 0; pt < 8; ++pt) {
            short8 bb = *(const short8*)&Xt[(pt * 16 + i16) * PITCH + ks * 32 + q * 8];
            acc[0][pt] = __builtin_amdgcn_mfma_f32_16x16x32_bf16(a0, bb, acc[0][pt], 0, 0, 0);
            acc[1][pt] = __builtin_amdgcn_mfma_f32_16x16x32_bf16(a1, bb, acc[1][pt], 0, 0, 0);
        }
    }
    __syncthreads();            // Xt dead -> reuse as Hs[c][p]

    unsigned short* Hs = Xt;
    unsigned short* h1tb = h1t + (size_t)(b * 128 + tile) * 16384;   // [p][k]
#pragma unroll
    for (int a = 0; a < 2; ++a) {
        int cb = wv * 32 + a * 16 + q * 4;
#pragma unroll
        for (int pt = 0; pt < 8; ++pt) {
            int p = pt * 16 + i16;
            ushort4 o;
            o.x = f2bf(acc[a][pt][0] + v_s[cb + 0]);
            o.y = f2bf(acc[a][pt][1] + v_s[cb + 1]);
            o.z = f2bf(acc[a][pt][2] + v_s[cb + 2]);
            o.w = f2bf(acc[a][pt][3] + v_s[cb + 3]);
            Hs[(cb + 0) * PITCH + p] = o.x;
            Hs[(cb + 1) * PITCH + p] = o.y;
            Hs[(cb + 2) * PITCH + p] = o.z;
            Hs[(cb + 3) * PITCH + p] = o.w;
            *(ushort4*)&h1tb[p * 128 + cb] = o;      // h1^T cache
        }
    }
    __syncthreads();

    // S partial: wave wv handles heads 2wv, 2wv+1 ; A==B frag (H H^T)
#pragma unroll
    for (int hh = 0; hh < 2; ++hh) {
        int h = wv * 2 + hh;
        f32x4 sacc = (f32x4){0.f, 0.f, 0.f, 0.f};
#pragma unroll
        for (int ks = 0; ks < 4; ++ks) {
            short8 f = *(const short8*)&Hs[(h * 16 + i16) * PITCH + ks * 32 + q * 8];
            sacc = __builtin_amdgcn_mfma_f32_16x16x32_bf16(f, f, sacc, 0, 0, 0);
        }
        float* sg = Sg + (b * 8 + h) * 256;
#pragma unroll
        for (int r = 0; r < 4; ++r)
            atomicAdd(&sg[(q * 4 + r) * 16 + i16], sacc[r]);
    }
}

// ---------------- K3: softmax + w_eff (bf16) ----------------
__global__ __launch_bounds__(256) void k_softmax_weff(const float* __restrict__ Sg,
                                                      const float* __restrict__ w_out,
                                                      unsigned short* __restrict__ weffb) {
    int b = blockIdx.x, t = threadIdx.x;
    __shared__ float W[2048];
    if (t < 128) {
        const float* row = Sg + b * 2048 + t * 16;
        float v[16];
        float m = -1e30f;
#pragma unroll
        for (int j = 0; j < 16; ++j) { v[j] = row[j] * 0.25f; m = fmaxf(m, v[j]); }
        float sum = 0.f;
#pragma unroll
        for (int j = 0; j < 16; ++j) { v[j] = __expf(v[j] - m); sum += v[j]; }
        float inv = 1.0f / sum;
#pragma unroll
        for (int j = 0; j < 16; ++j) W[t * 16 + j] = v[j] * inv;
    }
    __syncthreads();
    unsigned short* wo = weffb + b * 16384;
#pragma unroll 2
    for (int n = 0; n < 64; ++n) {
        int idx = t + n * 256;
        int c = idx >> 7, k = idx & 127;
        int h = k >> 4, j = k & 15;
        const float* wr = w_out + c * 128 + h * 16;
        const float* Wr = W + h * 256 + j;
        float a = 0.f;
#pragma unroll
        for (int i = 0; i < 16; ++i) a += wr[i] * Wr[i * 16];
        wo[idx] = f2bf(a);
    }
}

// ---------------- K4: out = x + b_out + w_eff @ h1 (h1 from cache) ----------------
__global__ __launch_bounds__(256, 4) void k_attn_out(const float* __restrict__ x,
                                                     const unsigned short* __restrict__ weffb,
                                                     const unsigned short* __restrict__ h1t,
                                                     const float* __restrict__ b_out,
                                                     float* __restrict__ out) {
    __shared__ unsigned short Hb[128 * PITCH];
    __shared__ float bo_s[128];

    const int t = threadIdx.x;
    const int lane = t & 63, wv = t >> 6;
    const int q = lane >> 4, i16 = lane & 15;
    const int b = blockIdx.x >> 7;
    const int tile = blockIdx.x & 127;
    const int p0 = tile << 7;

    if (t < 128) bo_s[t] = b_out[t];

    const unsigned short* ab = weffb + b * 16384;
    const unsigned short* h1tb = h1t + (size_t)(b * 128 + tile) * 16384;   // [p][k]

    f32x4 acc[2][8];
#pragma unroll
    for (int a = 0; a < 2; ++a)
#pragma unroll
        for (int pt = 0; pt < 8; ++pt) acc[a][pt] = (f32x4){0.f, 0.f, 0.f, 0.f};

#pragma unroll
    for (int ks = 0; ks < 4; ++ks) {
        short8 a0 = *(const short8*)&ab[(wv * 32 + i16) * 128 + ks * 32 + q * 8];
        short8 a1 = *(const short8*)&ab[(wv * 32 + 16 + i16) * 128 + ks * 32 + q * 8];
#pragma unroll
        for (int pt = 0; pt < 8; ++pt) {
            short8 bb = *(const short8*)&h1tb[(pt * 16 + i16) * 128 + ks * 32 + q * 8];
            acc[0][pt] = __builtin_amdgcn_mfma_f32_16x16x32_bf16(a0, bb, acc[0][pt], 0, 0, 0);
            acc[1][pt] = __builtin_amdgcn_mfma_f32_16x16x32_bf16(a1, bb, acc[1][pt], 0, 0, 0);
        }
    }
    __syncthreads();   // bo_s visible; Hb not yet read

    // h (+b_out) -> Hb[c][p] bf16
#pragma unroll
    for (int a = 0; a < 2; ++a) {
        int cb = wv * 32 + a * 16 + q * 4;
#pragma unroll
        for (int pt = 0; pt < 8; ++pt) {
            int p = pt * 16 + i16;
            Hb[(cb + 0) * PITCH + p] = f2bf(acc[a][pt][0] + bo_s[cb + 0]);
            Hb[(cb + 1) * PITCH + p] = f2bf(acc[a][pt][1] + bo_s[cb + 1]);
            Hb[(cb + 2) * PITCH + p] = f2bf(acc[a][pt][2] + bo_s[cb + 2]);
            Hb[(cb + 3) * PITCH + p] = f2bf(acc[a][pt][3] + bo_s[cb + 3]);
        }
    }
    __syncthreads();

    // epilogue: out = x + h, float4 both ways
    const float* xb = x + (size_t)b * (128 * NPOS) + p0;
    float* ob = out + (size_t)b * (128 * NPOS) + p0;
#pragma unroll
    for (int i = 0; i < 16; ++i) {
        int idx = t + i * 256;              // float4 chunks over [c][p] tile
        int c = idx >> 5, p4 = idx & 31;
        ushort4 hv = *(const ushort4*)&Hb[c * PITCH + p4 * 4];
        const float4 xv = *(const float4*)&xb[(size_t)c * NPOS + p4 * 4];
        float4 o;
        o.x = xv.x + bf2f(hv.x);
        o.y = xv.y + bf2f(hv.y);
        o.z = xv.z + bf2f(hv.z);
        o.w = xv.w + bf2f(hv.w);
        *(float4*)&ob[(size_t)c * NPOS + p4 * 4] = o;
    }
}

extern "C" void kernel_launch(void* const* d_in, const int* in_sizes, int n_in,
                              void* d_out, int out_size, void* d_ws, size_t ws_size,
                              hipStream_t stream) {
    const float* x    = (const float*)d_in[0];
    const float* gn_w = (const float*)d_in[1];
    const float* gn_b = (const float*)d_in[2];
    const float* w_in = (const float*)d_in[3];
    const float* b_in = (const float*)d_in[4];
    const float* w_out= (const float*)d_in[5];
    const float* b_out= (const float*)d_in[6];
    float* out = (float*)d_out;

    float* ws    = (float*)d_ws;
    float* stats = ws;                                        // 128 f
    float* Sg    = ws + 128;                                  // 16384 f
    float* vA    = ws + 16512;                                // 1024 f
    unsigned short* Asb   = (unsigned short*)(ws + 17536);    // 131072 us (8x128x128)
    unsigned short* weffb = (unsigned short*)(ws + 83072);    // 131072 us
    unsigned short* h1t   = (unsigned short*)(ws + 148608);   // 16.7M us (32 MiB)

    hipMemsetAsync(d_ws, 0, (128 + 16384) * sizeof(float), stream);
    k_stats<<<dim3(1024), dim3(256), 0, stream>>>(x, stats);
    k_prep<<<dim3(8), dim3(256), 0, stream>>>(stats, gn_w, gn_b, w_in, b_in, vA, Asb);
    k_gemm1_scores<<<dim3(1024), dim3(256), 0, stream>>>(x, Asb, vA, h1t, Sg);
    k_softmax_weff<<<dim3(8), dim3(256), 0, stream>>>(Sg, w_out, weffb);
    k_attn_out<<<dim3(1024), dim3(256), 0, stream>>>(x, weffb, h1t, b_out, out);
}